// Round 5
// baseline (163.017 us; speedup 1.0000x reference)
//
#include <hip/hip_runtime.h>
#include <math.h>

#define NFEAT 20

typedef float v4f __attribute__((ext_vector_type(4)));

__device__ __forceinline__ float bperm(unsigned int lane, float v) {
    return __int_as_float(
        __builtin_amdgcn_ds_bpermute((int)(lane << 2), __float_as_int(v)));
}

__global__ __launch_bounds__(256) void deepdft_expansion_kernel(
    const float* __restrict__ src,
    const float* __restrict__ tgt,
    float* __restrict__ out,
    unsigned int N, unsigned int M)
{
    const float CUT  = 4.0f;
    const float EPS  = 1e-11f;
    const float BOHR = 0.5291772105638411f;
    const float PI_F = 3.14159265358979323846f;

    const unsigned int total = N * M;

    float* __restrict__ dist_o = out;
    float* __restrict__ dir_o  = out + (size_t)total;          // [total][3]
    float* __restrict__ mask_o = out + (size_t)4 * total;      // [total]
    float* __restrict__ exp_o  = out + (size_t)5 * total;      // [total][20]

    const unsigned int lane = threadIdx.x & 63u;
    const unsigned int wavesPerGrid = (gridDim.x * blockDim.x) >> 6;
    const unsigned int wtiles = (total + 63u) >> 6;

    for (unsigned int w = (blockIdx.x * blockDim.x + threadIdx.x) >> 6;
         w < wtiles; w += wavesPerGrid) {
        const unsigned int base = w << 6;          // first pair of this wave-tile
        const unsigned int idx  = base + lane;
        // keep all 64 lanes active (bpermute sources must be valid): clamp
        const unsigned int cidx = (idx < total) ? idx : (total - 1u);

        unsigned int n = cidx / M;
        unsigned int m = cidx - n * M;

        float sx = src[3u*n + 0], sy = src[3u*n + 1], sz = src[3u*n + 2];
        float tx = tgt[3u*m + 0], ty = tgt[3u*m + 1], tz = tgt[3u*m + 2];

        float dx = tx - sx, dy = ty - sy, dz = tz - sz;
        float d2   = fmaf(dx, dx, fmaf(dy, dy, dz * dz));
        float dist = sqrtf(d2);
        float inv  = 1.0f / (dist + EPS);

        if (idx < total) {
            __builtin_nontemporal_store(dist, &dist_o[idx]);   // coalesced, L2-bypass
            __builtin_nontemporal_store((dist < CUT) ? 1.0f : 0.0f,
                                        &mask_o[idx]);
        }

        float ux = dx * inv, uy = dy * inv, uz = dz * inv;
        float d    = fmaf(dist, BOHR, EPS);
        float invd = 1.0f / d;
        float x    = (PI_F / CUT) * d;                   // x = pi*d/CUT

        // ---- direction: wave-local transpose [64][3] -> [192] linear ----
        {
            float* gdir = dir_o + (size_t)3 * base;
            #pragma unroll
            for (int k = 0; k < 3; ++k) {
                unsigned int e = lane + 64u * (unsigned)k;    // e < 192
                unsigned int p = (e * 10923u) >> 15;          // e / 3
                unsigned int c = e - 3u * p;                  // e % 3
                float vx = bperm(p, ux);
                float vy = bperm(p, uy);
                float vz = bperm(p, uz);
                float val = (c == 0u) ? vx : ((c == 1u) ? vy : vz);
                if (base + p < total)
                    __builtin_nontemporal_store(val, &gdir[e]);
            }
        }

        // ---- expansion: regenerate sines in output order, v4f stores ----
        {
            v4f* gexp = reinterpret_cast<v4f*>(exp_o) + (size_t)5 * base;
            #pragma unroll
            for (int k = 0; k < 5; ++k) {
                unsigned int j = lane + 64u * (unsigned)k;    // v4 idx < 320
                unsigned int p = (j * 6554u) >> 15;           // j / 5
                unsigned int g = j - 5u * p;                  // j % 5
                float xv = bperm(p, x);
                float iv = bperm(p, invd);
                float n0 = (float)(4u * g + 1u);              // first n of group
                v4f v;
                v.x = __sinf( n0         * xv) * iv;
                v.y = __sinf((n0 + 1.0f) * xv) * iv;
                v.z = __sinf((n0 + 2.0f) * xv) * iv;
                v.w = __sinf((n0 + 3.0f) * xv) * iv;
                if (base + p < total)
                    __builtin_nontemporal_store(v, &gexp[j]); // 1 KiB/wave, L2-bypass
            }
        }
    }
}

extern "C" void kernel_launch(void* const* d_in, const int* in_sizes, int n_in,
                              void* d_out, int out_size, void* d_ws, size_t ws_size,
                              hipStream_t stream) {
    const float* src = (const float*)d_in[0];   // [1, N, 3] float32
    const float* tgt = (const float*)d_in[1];   // [1, M, 3] float32
    float* out = (float*)d_out;

    unsigned int N = (unsigned int)(in_sizes[0] / 3);
    unsigned int M = (unsigned int)(in_sizes[1] / 3);
    unsigned int total = N * M;

    const unsigned int block = 256;
    unsigned int wtiles = (total + 63u) >> 6;          // one wave per 64 pairs
    unsigned int blocks = (wtiles + (block / 64) - 1) / (block / 64);
    if (blocks > 2048u) blocks = 2048u;                // grid-stride the rest

    deepdft_expansion_kernel<<<blocks, block, 0, stream>>>(src, tgt, out, N, M);
}